// Round 1
// baseline (692.456 us; speedup 1.0000x reference)
//
#include <hip/hip_runtime.h>
#include <stdint.h>

#define M_TOT 2048   // B*C
#define N_TOT 16384  // B*F
#define K_TOT 512    // D

// ---------------- Kernel 1: row norms ----------------
// waves 0..2047: normalize c_feats rows -> xn.  waves 2048..18431: ||f_row|| -> normf.
__global__ __launch_bounds__(256) void norm_kernel(
    const float* __restrict__ c_feats, const float* __restrict__ f_feats,
    float* __restrict__ xn, float* __restrict__ normf)
{
    int wave = blockIdx.x * 4 + (threadIdx.x >> 6);
    int lane = threadIdx.x & 63;
    if (wave < 2048) {
        const float* row = c_feats + (size_t)wave * K_TOT;
        float4 v0 = ((const float4*)row)[lane];
        float4 v1 = ((const float4*)row)[lane + 64];
        double ss = (double)v0.x * v0.x + (double)v0.y * v0.y +
                    (double)v0.z * v0.z + (double)v0.w * v0.w +
                    (double)v1.x * v1.x + (double)v1.y * v1.y +
                    (double)v1.z * v1.z + (double)v1.w * v1.w;
        #pragma unroll
        for (int off = 32; off; off >>= 1) ss += __shfl_down(ss, off);
        double tot = __shfl(ss, 0);
        float nrm = sqrtf((float)tot);
        float4 o0, o1;
        o0.x = v0.x / nrm; o0.y = v0.y / nrm; o0.z = v0.z / nrm; o0.w = v0.w / nrm;
        o1.x = v1.x / nrm; o1.y = v1.y / nrm; o1.z = v1.z / nrm; o1.w = v1.w / nrm;
        float4* orow = (float4*)(xn + (size_t)wave * K_TOT);
        orow[lane] = o0;
        orow[lane + 64] = o1;
    } else if (wave < 18432) {
        int fr = wave - 2048;
        const float* row = f_feats + (size_t)fr * K_TOT;
        float4 v0 = ((const float4*)row)[lane];
        float4 v1 = ((const float4*)row)[lane + 64];
        double ss = (double)v0.x * v0.x + (double)v0.y * v0.y +
                    (double)v0.z * v0.z + (double)v0.w * v0.w +
                    (double)v1.x * v1.x + (double)v1.y * v1.y +
                    (double)v1.z * v1.z + (double)v1.w * v1.w;
        #pragma unroll
        for (int off = 32; off; off >>= 1) ss += __shfl_down(ss, off);
        if (lane == 0) normf[fr] = sqrtf((float)ss);
    }
}

// ---------------- Kernel 2: fp32 GEMM, S staged into out ----------------
// out[((m*128+n)*16+i)*128+j] = dot(xn[m*16+i], f[n*128+j]) / (j<=i ? ||f_row|| : 1)
#define BM 128
#define BN 64
#define BK 32

__global__ __launch_bounds__(256) void gemm_kernel(
    const float* __restrict__ A,      // xn [2048][512]
    const float* __restrict__ Bmat,   // f_feats [16384][512]
    const float* __restrict__ normf,  // [16384]
    float* __restrict__ out)
{
    __shared__ __align__(16) float As[BK][BM + 4];  // transposed: [k][row]
    __shared__ __align__(16) float Bs[BK][BN + 4];
    const int t = threadIdx.x;
    const int gm0 = blockIdx.y * BM;
    const int gn0 = blockIdx.x * BN;
    const int tx = t & 15;   // -> 4 cols
    const int ty = t >> 4;   // -> 8 rows
    const int kq = t & 7;    // float4 index along K
    const int rw = t >> 3;   // 0..31

    float acc[8][4];
    #pragma unroll
    for (int r = 0; r < 8; ++r)
        #pragma unroll
        for (int c = 0; c < 4; ++c) acc[r][c] = 0.f;

    for (int k0 = 0; k0 < K_TOT; k0 += BK) {
        #pragma unroll
        for (int r = 0; r < 4; ++r) {
            int row = rw + r * 32;
            float4 v = *(const float4*)(A + (size_t)(gm0 + row) * K_TOT + k0 + kq * 4);
            As[kq * 4 + 0][row] = v.x;
            As[kq * 4 + 1][row] = v.y;
            As[kq * 4 + 2][row] = v.z;
            As[kq * 4 + 3][row] = v.w;
        }
        #pragma unroll
        for (int r = 0; r < 2; ++r) {
            int row = rw + r * 32;
            float4 v = *(const float4*)(Bmat + (size_t)(gn0 + row) * K_TOT + k0 + kq * 4);
            Bs[kq * 4 + 0][row] = v.x;
            Bs[kq * 4 + 1][row] = v.y;
            Bs[kq * 4 + 2][row] = v.z;
            Bs[kq * 4 + 3][row] = v.w;
        }
        __syncthreads();
        #pragma unroll
        for (int k = 0; k < BK; ++k) {
            float4 a0 = *(const float4*)&As[k][ty * 8];
            float4 a1 = *(const float4*)&As[k][ty * 8 + 4];
            float4 b  = *(const float4*)&Bs[k][tx * 4];
            float av[8] = {a0.x, a0.y, a0.z, a0.w, a1.x, a1.y, a1.z, a1.w};
            float bv[4] = {b.x, b.y, b.z, b.w};
            #pragma unroll
            for (int r = 0; r < 8; ++r)
                #pragma unroll
                for (int c = 0; c < 4; ++c)
                    acc[r][c] = fmaf(av[r], bv[c], acc[r][c]);
        }
        __syncthreads();
    }

    const int gc0 = gn0 + tx * 4;
    const int nn = gc0 >> 7;
    const int j0 = gc0 & 127;
    float4 nf = {1.f, 1.f, 1.f, 1.f};
    if (j0 < 16) nf = *(const float4*)(normf + gc0);
    #pragma unroll
    for (int r = 0; r < 8; ++r) {
        int gr = gm0 + ty * 8 + r;
        int mm = gr >> 4, ii = gr & 15;
        float4 v = {acc[r][0], acc[r][1], acc[r][2], acc[r][3]};
        if (j0 < 16) {
            if (j0 + 0 <= ii) v.x /= nf.x;
            if (j0 + 1 <= ii) v.y /= nf.y;
            if (j0 + 2 <= ii) v.z /= nf.z;
            if (j0 + 3 <= ii) v.w /= nf.w;
        }
        size_t base = ((size_t)(mm * 128 + nn) * 16 + ii) * 128 + j0;
        *(float4*)(out + base) = v;
    }
}

// ---------------- Kernel 3: DTW DP + backtrack, in-place over S ----------------
// One wave per problem p. Lane l owns 0-based cols 2l, 2l+1 (1-based j = 2l+1, 2l+2).
__global__ __launch_bounds__(256) void dtw_kernel(float* __restrict__ buf)
{
    const int lane = threadIdx.x & 63;
    const int p = blockIdx.x * 4 + (threadIdx.x >> 6);
    float* tile = buf + (size_t)p * 2048;
    const double NEG = -1e300;
    double pA = NEG, pB = NEG;   // D[i-1][jA], D[i-1][jB]
    unsigned mvA = 0, mvB = 0;   // 2-bit moves per row for each owned col

    for (int i = 1; i <= 16; ++i) {
        float2 s = ((const float2*)tile)[(i - 1) * 64 + lane];
        double s1 = (double)s.x;
        double s2 = s1 + (double)s.y;
        // inclusive sum-scan of per-lane pair sums -> exclusive prefix
        double t = s2;
        #pragma unroll
        for (int off = 1; off < 64; off <<= 1) {
            double u = __shfl_up(t, off);
            if (lane >= off) t += u;
        }
        double excl = t - s2;        // Ccum[jA-1]
        double C1 = excl + s1;       // Ccum[jA]
        double C2 = excl + s2;       // Ccum[jB]
        double pm1 = __shfl_up(pB, 1);           // D[i-1][jA-1]
        if (lane == 0) pm1 = (i == 1) ? 0.0 : NEG;
        double A1 = fmax(pm1, pA);
        double A2 = fmax(pA, pB);
        double T1 = A1 - excl;
        double T2 = A2 - C1;
        double g = fmax(T1, T2);
        #pragma unroll
        for (int off = 1; off < 64; off <<= 1) {
            double u = __shfl_up(g, off);
            if (lane >= off) g = fmax(g, u);
        }
        double gex = __shfl_up(g, 1);            // cummax through jB of prev lane
        if (lane == 0) gex = NEG;
        double M1 = fmax(gex, T1);
        double M2 = fmax(M1, T2);
        double nA = C1 + M1;         // D[i][jA]
        double nB = C2 + M2;         // D[i][jB]
        double lA = __shfl_up(nB, 1);            // D[i][jA-1]
        if (lane == 0) lA = NEG;
        // argmax(up, left, diag) with first-max tie-break
        int m1 = (pA >= lA && pA >= pm1) ? 0 : ((lA >= pm1) ? 1 : 2);
        int m2v = (pB >= nA && pB >= pA) ? 0 : ((nA >= pA) ? 1 : 2);
        mvA |= (unsigned)m1 << (2 * (i - 1));
        mvB |= (unsigned)m2v << (2 * (i - 1));
        pA = nA; pB = nB;
    }

    // backtrack from (16,128) to (0,0); mark cell (i-1, j-1) each step
    unsigned maskA = 0, maskB = 0;
    int i = 16, j = 128;
    for (int step = 0; step < 160; ++step) {
        if (i <= 0 && j <= 0) break;
        int col = j - 1, row = i - 1;
        if (row < 0) { j -= 1; continue; }   // unreachable guards
        if (col < 0) { i -= 1; continue; }
        int owner = col >> 1, sub = col & 1;
        if (lane == owner) {
            if (sub) maskB |= 1u << row; else maskA |= 1u << row;
        }
        unsigned w = __shfl(sub ? mvB : mvA, owner);
        int m = (int)((w >> (2 * row)) & 3u);
        i -= (m == 1) ? 0 : 1;
        j -= (m == 0) ? 0 : 1;
    }

    // overwrite the S tile with the 0/1 mask (fully covers d_out)
    #pragma unroll
    for (int r = 0; r < 16; ++r) {
        float2 v;
        v.x = (float)((maskA >> r) & 1u);
        v.y = (float)((maskB >> r) & 1u);
        ((float2*)tile)[r * 64 + lane] = v;
    }
}

extern "C" void kernel_launch(void* const* d_in, const int* in_sizes, int n_in,
                              void* d_out, int out_size, void* d_ws, size_t ws_size,
                              hipStream_t stream)
{
    const float* c_feats = (const float*)d_in[0];
    const float* f_feats = (const float*)d_in[1];
    float* out = (float*)d_out;
    float* xn = (float*)d_ws;                       // 2048*512 fp32 = 4 MB
    float* normf = xn + (size_t)M_TOT * K_TOT;      // 16384 fp32

    norm_kernel<<<4608, 256, 0, stream>>>(c_feats, f_feats, xn, normf);
    dim3 g(N_TOT / BN, M_TOT / BM);
    gemm_kernel<<<g, 256, 0, stream>>>(xn, f_feats, normf, out);
    dtw_kernel<<<16384 / 4, 256, 0, stream>>>(out);
}

// Round 2
// 386.470 us; speedup vs baseline: 1.7917x; 1.7917x over previous
//
#include <hip/hip_runtime.h>
#include <stdint.h>

#define M_TOT 2048   // B*C
#define N_TOT 16384  // B*F
#define K_TOT 512    // D

typedef _Float16 f16x8 __attribute__((ext_vector_type(8)));
typedef float f32x4 __attribute__((ext_vector_type(4)));

#define AS1 __attribute__((address_space(1)))
#define AS3 __attribute__((address_space(3)))

__device__ __forceinline__ void ld_lds16(const void* g, void* l) {
    __builtin_amdgcn_global_load_lds((const AS1 void*)g, (AS3 void*)l, 16, 0, 0);
}

// ---------------- Kernel 1: norms + f16 hi/lo split planes ----------------
// waves 0..2047: xn = c/||c|| -> Ah/Al.  waves 2048..18431: f -> Bh/Bl, ||f|| -> normf.
__device__ __forceinline__ void split4(float x0, float x1, float x2, float x3,
                                       uint2* hs, uint2* ls) {
    union U { _Float16 h[4]; uint2 u; } H, L;
    _Float16 h0 = (_Float16)x0; H.h[0] = h0; L.h[0] = (_Float16)(x0 - (float)h0);
    _Float16 h1 = (_Float16)x1; H.h[1] = h1; L.h[1] = (_Float16)(x1 - (float)h1);
    _Float16 h2 = (_Float16)x2; H.h[2] = h2; L.h[2] = (_Float16)(x2 - (float)h2);
    _Float16 h3 = (_Float16)x3; H.h[3] = h3; L.h[3] = (_Float16)(x3 - (float)h3);
    *hs = H.u; *ls = L.u;
}

__global__ __launch_bounds__(256) void norm_split_kernel(
    const float* __restrict__ c_feats, const float* __restrict__ f_feats,
    _Float16* __restrict__ Ah, _Float16* __restrict__ Al,
    _Float16* __restrict__ Bh, _Float16* __restrict__ Bl,
    float* __restrict__ normf)
{
    int wave = blockIdx.x * 4 + (threadIdx.x >> 6);
    int lane = threadIdx.x & 63;
    if (wave < 2048) {
        const float* row = c_feats + (size_t)wave * K_TOT;
        float4 v0 = ((const float4*)row)[lane];
        float4 v1 = ((const float4*)row)[lane + 64];
        double ss = (double)v0.x * v0.x + (double)v0.y * v0.y +
                    (double)v0.z * v0.z + (double)v0.w * v0.w +
                    (double)v1.x * v1.x + (double)v1.y * v1.y +
                    (double)v1.z * v1.z + (double)v1.w * v1.w;
        #pragma unroll
        for (int off = 32; off; off >>= 1) ss += __shfl_down(ss, off);
        double tot = __shfl(ss, 0);
        float nrm = sqrtf((float)tot);
        // fp32 division per element (bit-matches round-1 path that gave absmax 0)
        float a0 = v0.x / nrm, a1 = v0.y / nrm, a2 = v0.z / nrm, a3 = v0.w / nrm;
        float b0 = v1.x / nrm, b1 = v1.y / nrm, b2 = v1.z / nrm, b3 = v1.w / nrm;
        uint2 h, l;
        split4(a0, a1, a2, a3, &h, &l);
        ((uint2*)(Ah + (size_t)wave * K_TOT))[lane] = h;
        ((uint2*)(Al + (size_t)wave * K_TOT))[lane] = l;
        split4(b0, b1, b2, b3, &h, &l);
        ((uint2*)(Ah + (size_t)wave * K_TOT))[lane + 64] = h;
        ((uint2*)(Al + (size_t)wave * K_TOT))[lane + 64] = l;
    } else if (wave < 18432) {
        int fr = wave - 2048;
        const float* row = f_feats + (size_t)fr * K_TOT;
        float4 v0 = ((const float4*)row)[lane];
        float4 v1 = ((const float4*)row)[lane + 64];
        double ss = (double)v0.x * v0.x + (double)v0.y * v0.y +
                    (double)v0.z * v0.z + (double)v0.w * v0.w +
                    (double)v1.x * v1.x + (double)v1.y * v1.y +
                    (double)v1.z * v1.z + (double)v1.w * v1.w;
        #pragma unroll
        for (int off = 32; off; off >>= 1) ss += __shfl_down(ss, off);
        if (lane == 0) normf[fr] = sqrtf((float)ss);
        uint2 h, l;
        split4(v0.x, v0.y, v0.z, v0.w, &h, &l);
        ((uint2*)(Bh + (size_t)fr * K_TOT))[lane] = h;
        ((uint2*)(Bl + (size_t)fr * K_TOT))[lane] = l;
        split4(v1.x, v1.y, v1.z, v1.w, &h, &l);
        ((uint2*)(Bh + (size_t)fr * K_TOT))[lane + 64] = h;
        ((uint2*)(Bl + (size_t)fr * K_TOT))[lane + 64] = l;
    }
}

// ---------------- Kernel 2: split-f16 MFMA GEMM, S staged into out ----------------
// C[gm][gn] = dot(xn[gm], f[gn]) via ah*bh + ah*bl + al*bh, fp32 acc.
// out[((mm*128+nn)*16+ii)*128+jj], mm=gm>>4, ii=gm&15, nn=gn>>7, jj=gn&127.
__global__ __launch_bounds__(256, 2) void mfma_gemm_kernel(
    const _Float16* __restrict__ Ah, const _Float16* __restrict__ Al,
    const _Float16* __restrict__ Bh, const _Float16* __restrict__ Bl,
    const float* __restrict__ normf,
    float* __restrict__ out)
{
    __shared__ _Float16 sAh[128 * 32];
    __shared__ _Float16 sAl[128 * 32];
    __shared__ _Float16 sBh[128 * 32];
    __shared__ _Float16 sBl[128 * 32];

    const int t = threadIdx.x;
    const int w = t >> 6, lane = t & 63;
    const int gm0 = blockIdx.y * 128, gn0 = blockIdx.x * 128;
    const int wm = (w & 1) * 64, wn = (w >> 1) * 64;
    const int fr = lane & 15, fq = lane >> 4;

    f32x4 acc[4][4] = {};

    const int l0 = w * 128 + lane;

    for (int k0 = 0; k0 < K_TOT; k0 += 32) {
        #pragma unroll
        for (int c = 0; c < 2; ++c) {
            int l = l0 + c * 64;
            int row = l >> 2, kq = l & 3;
            size_t goffA = (size_t)(gm0 + row) * K_TOT + k0 + kq * 8;
            size_t goffB = (size_t)(gn0 + row) * K_TOT + k0 + kq * 8;
            ld_lds16(Ah + goffA, sAh + (size_t)l * 8);
            ld_lds16(Al + goffA, sAl + (size_t)l * 8);
            ld_lds16(Bh + goffB, sBh + (size_t)l * 8);
            ld_lds16(Bl + goffB, sBl + (size_t)l * 8);
        }
        __syncthreads();

        f16x8 fah[4], fal[4], fbh[4], fbl[4];
        #pragma unroll
        for (int x = 0; x < 4; ++x) {
            int ar = (wm + x * 16 + fr) * 32 + fq * 8;
            int br = (wn + x * 16 + fr) * 32 + fq * 8;
            fah[x] = *(const f16x8*)(sAh + ar);
            fal[x] = *(const f16x8*)(sAl + ar);
            fbh[x] = *(const f16x8*)(sBh + br);
            fbl[x] = *(const f16x8*)(sBl + br);
        }
        #pragma unroll
        for (int mi = 0; mi < 4; ++mi)
            #pragma unroll
            for (int ni = 0; ni < 4; ++ni) {
                acc[mi][ni] = __builtin_amdgcn_mfma_f32_16x16x32_f16(fah[mi], fbl[ni], acc[mi][ni], 0, 0, 0);
                acc[mi][ni] = __builtin_amdgcn_mfma_f32_16x16x32_f16(fal[mi], fbh[ni], acc[mi][ni], 0, 0, 0);
                acc[mi][ni] = __builtin_amdgcn_mfma_f32_16x16x32_f16(fah[mi], fbh[ni], acc[mi][ni], 0, 0, 0);
            }
        __syncthreads();
    }

    // epilogue: triangle divide by ||f|| and scatter to out layout
    const int nn = blockIdx.x;  // gn0 == nn*128
    #pragma unroll
    for (int ni = 0; ni < 4; ++ni) {
        int col = wn + ni * 16 + fr;       // local col == jj (0..127)
        bool cn = (col < 16);
        float nf = 1.f;
        if (cn) nf = normf[gn0 + col];
        #pragma unroll
        for (int mi = 0; mi < 4; ++mi) {
            #pragma unroll
            for (int r = 0; r < 4; ++r) {
                int gm = gm0 + wm + mi * 16 + fq * 4 + r;
                int mm = gm >> 4, ii = gm & 15;
                float v = acc[mi][ni][r];
                if (cn && col <= ii) v /= nf;
                out[(((size_t)mm * 128 + nn) * 16 + ii) * 128 + col] = v;
            }
        }
    }
}

// ---------------- Kernel 3: DTW DP + backtrack, in-place over S ----------------
// One wave per problem p. Lane l owns 0-based cols 2l, 2l+1 (1-based j = 2l+1, 2l+2).
__global__ __launch_bounds__(256) void dtw_kernel(float* __restrict__ buf)
{
    const int lane = threadIdx.x & 63;
    const int p = blockIdx.x * 4 + (threadIdx.x >> 6);
    float* tile = buf + (size_t)p * 2048;
    const double NEG = -1e300;
    double pA = NEG, pB = NEG;   // D[i-1][jA], D[i-1][jB]
    unsigned mvA = 0, mvB = 0;   // 2-bit moves per row for each owned col

    for (int i = 1; i <= 16; ++i) {
        float2 s = ((const float2*)tile)[(i - 1) * 64 + lane];
        double s1 = (double)s.x;
        double s2 = s1 + (double)s.y;
        // inclusive sum-scan of per-lane pair sums -> exclusive prefix
        double t = s2;
        #pragma unroll
        for (int off = 1; off < 64; off <<= 1) {
            double u = __shfl_up(t, off);
            if (lane >= off) t += u;
        }
        double excl = t - s2;        // Ccum[jA-1]
        double C1 = excl + s1;       // Ccum[jA]
        double C2 = excl + s2;       // Ccum[jB]
        double pm1 = __shfl_up(pB, 1);           // D[i-1][jA-1]
        if (lane == 0) pm1 = (i == 1) ? 0.0 : NEG;
        double A1 = fmax(pm1, pA);
        double A2 = fmax(pA, pB);
        double T1 = A1 - excl;
        double T2 = A2 - C1;
        double g = fmax(T1, T2);
        #pragma unroll
        for (int off = 1; off < 64; off <<= 1) {
            double u = __shfl_up(g, off);
            if (lane >= off) g = fmax(g, u);
        }
        double gex = __shfl_up(g, 1);            // cummax through jB of prev lane
        if (lane == 0) gex = NEG;
        double M1 = fmax(gex, T1);
        double M2 = fmax(M1, T2);
        double nA = C1 + M1;         // D[i][jA]
        double nB = C2 + M2;         // D[i][jB]
        double lA = __shfl_up(nB, 1);            // D[i][jA-1]
        if (lane == 0) lA = NEG;
        // argmax(up, left, diag) with first-max tie-break
        int m1 = (pA >= lA && pA >= pm1) ? 0 : ((lA >= pm1) ? 1 : 2);
        int m2v = (pB >= nA && pB >= pA) ? 0 : ((nA >= pA) ? 1 : 2);
        mvA |= (unsigned)m1 << (2 * (i - 1));
        mvB |= (unsigned)m2v << (2 * (i - 1));
        pA = nA; pB = nB;
    }

    // backtrack from (16,128) to (0,0); mark cell (i-1, j-1) each step
    unsigned maskA = 0, maskB = 0;
    int i = 16, j = 128;
    for (int step = 0; step < 160; ++step) {
        if (i <= 0 && j <= 0) break;
        int col = j - 1, row = i - 1;
        if (row < 0) { j -= 1; continue; }   // unreachable guards
        if (col < 0) { i -= 1; continue; }
        int owner = col >> 1, sub = col & 1;
        if (lane == owner) {
            if (sub) maskB |= 1u << row; else maskA |= 1u << row;
        }
        unsigned wmv = __shfl(sub ? mvB : mvA, owner);
        int m = (int)((wmv >> (2 * row)) & 3u);
        i -= (m == 1) ? 0 : 1;
        j -= (m == 0) ? 0 : 1;
    }

    // overwrite the S tile with the 0/1 mask (fully covers d_out)
    #pragma unroll
    for (int r = 0; r < 16; ++r) {
        float2 v;
        v.x = (float)((maskA >> r) & 1u);
        v.y = (float)((maskB >> r) & 1u);
        ((float2*)tile)[r * 64 + lane] = v;
    }
}

extern "C" void kernel_launch(void* const* d_in, const int* in_sizes, int n_in,
                              void* d_out, int out_size, void* d_ws, size_t ws_size,
                              hipStream_t stream)
{
    const float* c_feats = (const float*)d_in[0];
    const float* f_feats = (const float*)d_in[1];
    float* out = (float*)d_out;

    _Float16* Ah = (_Float16*)d_ws;                       // 2048*512 f16 = 2 MB
    _Float16* Al = Ah + (size_t)M_TOT * K_TOT;            // 2 MB
    _Float16* Bh = Al + (size_t)M_TOT * K_TOT;            // 16.8 MB
    _Float16* Bl = Bh + (size_t)N_TOT * K_TOT;            // 16.8 MB
    float* normf = (float*)(Bl + (size_t)N_TOT * K_TOT);  // 64 KB

    norm_split_kernel<<<4608, 256, 0, stream>>>(c_feats, f_feats, Ah, Al, Bh, Bl, normf);
    dim3 g(N_TOT / 128, M_TOT / 128);
    mfma_gemm_kernel<<<g, 256, 0, stream>>>(Ah, Al, Bh, Bl, normf, out);
    dtw_kernel<<<16384 / 4, 256, 0, stream>>>(out);
}

// Round 3
// 360.952 us; speedup vs baseline: 1.9184x; 1.0707x over previous
//
#include <hip/hip_runtime.h>
#include <stdint.h>

#define M_TOT 2048   // B*C
#define N_TOT 16384  // B*F
#define K_TOT 512    // D

typedef _Float16 f16x8 __attribute__((ext_vector_type(8)));
typedef float f32x4 __attribute__((ext_vector_type(4)));

#define AS1 __attribute__((address_space(1)))
#define AS3 __attribute__((address_space(3)))

__device__ __forceinline__ void ld_lds16(const void* g, void* l) {
    __builtin_amdgcn_global_load_lds((const AS1 void*)g, (AS3 void*)l, 16, 0, 0);
}

// ---------------- Kernel 1: norms + f16 hi/lo split planes ----------------
__device__ __forceinline__ void split4(float x0, float x1, float x2, float x3,
                                       uint2* hs, uint2* ls) {
    union U { _Float16 h[4]; uint2 u; } H, L;
    _Float16 h0 = (_Float16)x0; H.h[0] = h0; L.h[0] = (_Float16)(x0 - (float)h0);
    _Float16 h1 = (_Float16)x1; H.h[1] = h1; L.h[1] = (_Float16)(x1 - (float)h1);
    _Float16 h2 = (_Float16)x2; H.h[2] = h2; L.h[2] = (_Float16)(x2 - (float)h2);
    _Float16 h3 = (_Float16)x3; H.h[3] = h3; L.h[3] = (_Float16)(x3 - (float)h3);
    *hs = H.u; *ls = L.u;
}

__global__ __launch_bounds__(256) void norm_split_kernel(
    const float* __restrict__ c_feats, const float* __restrict__ f_feats,
    _Float16* __restrict__ Ah, _Float16* __restrict__ Al,
    _Float16* __restrict__ Bh, _Float16* __restrict__ Bl,
    float* __restrict__ normf)
{
    int wave = blockIdx.x * 4 + (threadIdx.x >> 6);
    int lane = threadIdx.x & 63;
    if (wave < 2048) {
        const float* row = c_feats + (size_t)wave * K_TOT;
        float4 v0 = ((const float4*)row)[lane];
        float4 v1 = ((const float4*)row)[lane + 64];
        double ss = (double)v0.x * v0.x + (double)v0.y * v0.y +
                    (double)v0.z * v0.z + (double)v0.w * v0.w +
                    (double)v1.x * v1.x + (double)v1.y * v1.y +
                    (double)v1.z * v1.z + (double)v1.w * v1.w;
        #pragma unroll
        for (int off = 32; off; off >>= 1) ss += __shfl_down(ss, off);
        double tot = __shfl(ss, 0);
        float nrm = sqrtf((float)tot);
        float a0 = v0.x / nrm, a1 = v0.y / nrm, a2 = v0.z / nrm, a3 = v0.w / nrm;
        float b0 = v1.x / nrm, b1 = v1.y / nrm, b2 = v1.z / nrm, b3 = v1.w / nrm;
        uint2 h, l;
        split4(a0, a1, a2, a3, &h, &l);
        ((uint2*)(Ah + (size_t)wave * K_TOT))[lane] = h;
        ((uint2*)(Al + (size_t)wave * K_TOT))[lane] = l;
        split4(b0, b1, b2, b3, &h, &l);
        ((uint2*)(Ah + (size_t)wave * K_TOT))[lane + 64] = h;
        ((uint2*)(Al + (size_t)wave * K_TOT))[lane + 64] = l;
    } else if (wave < 18432) {
        int fr = wave - 2048;
        const float* row = f_feats + (size_t)fr * K_TOT;
        float4 v0 = ((const float4*)row)[lane];
        float4 v1 = ((const float4*)row)[lane + 64];
        double ss = (double)v0.x * v0.x + (double)v0.y * v0.y +
                    (double)v0.z * v0.z + (double)v0.w * v0.w +
                    (double)v1.x * v1.x + (double)v1.y * v1.y +
                    (double)v1.z * v1.z + (double)v1.w * v1.w;
        #pragma unroll
        for (int off = 32; off; off >>= 1) ss += __shfl_down(ss, off);
        if (lane == 0) normf[fr] = sqrtf((float)ss);
        uint2 h, l;
        split4(v0.x, v0.y, v0.z, v0.w, &h, &l);
        ((uint2*)(Bh + (size_t)fr * K_TOT))[lane] = h;
        ((uint2*)(Bl + (size_t)fr * K_TOT))[lane] = l;
        split4(v1.x, v1.y, v1.z, v1.w, &h, &l);
        ((uint2*)(Bh + (size_t)fr * K_TOT))[lane + 64] = h;
        ((uint2*)(Bl + (size_t)fr * K_TOT))[lane + 64] = l;
    }
}

// ---------------- Kernel 2: split-f16 MFMA GEMM, S staged into out ----------------
__global__ __launch_bounds__(256, 2) void mfma_gemm_kernel(
    const _Float16* __restrict__ Ah, const _Float16* __restrict__ Al,
    const _Float16* __restrict__ Bh, const _Float16* __restrict__ Bl,
    const float* __restrict__ normf,
    float* __restrict__ out)
{
    __shared__ _Float16 sAh[128 * 32];
    __shared__ _Float16 sAl[128 * 32];
    __shared__ _Float16 sBh[128 * 32];
    __shared__ _Float16 sBl[128 * 32];

    const int t = threadIdx.x;
    const int w = t >> 6, lane = t & 63;
    const int gm0 = blockIdx.y * 128, gn0 = blockIdx.x * 128;
    const int wm = (w & 1) * 64, wn = (w >> 1) * 64;
    const int fr = lane & 15, fq = lane >> 4;

    f32x4 acc[4][4] = {};

    const int l0 = w * 128 + lane;

    for (int k0 = 0; k0 < K_TOT; k0 += 32) {
        #pragma unroll
        for (int c = 0; c < 2; ++c) {
            int l = l0 + c * 64;
            int row = l >> 2, kq = l & 3;
            size_t goffA = (size_t)(gm0 + row) * K_TOT + k0 + kq * 8;
            size_t goffB = (size_t)(gn0 + row) * K_TOT + k0 + kq * 8;
            ld_lds16(Ah + goffA, sAh + (size_t)l * 8);
            ld_lds16(Al + goffA, sAl + (size_t)l * 8);
            ld_lds16(Bh + goffB, sBh + (size_t)l * 8);
            ld_lds16(Bl + goffB, sBl + (size_t)l * 8);
        }
        __syncthreads();

        f16x8 fah[4], fal[4], fbh[4], fbl[4];
        #pragma unroll
        for (int x = 0; x < 4; ++x) {
            int ar = (wm + x * 16 + fr) * 32 + fq * 8;
            int br = (wn + x * 16 + fr) * 32 + fq * 8;
            fah[x] = *(const f16x8*)(sAh + ar);
            fal[x] = *(const f16x8*)(sAl + ar);
            fbh[x] = *(const f16x8*)(sBh + br);
            fbl[x] = *(const f16x8*)(sBl + br);
        }
        #pragma unroll
        for (int mi = 0; mi < 4; ++mi)
            #pragma unroll
            for (int ni = 0; ni < 4; ++ni) {
                acc[mi][ni] = __builtin_amdgcn_mfma_f32_16x16x32_f16(fah[mi], fbl[ni], acc[mi][ni], 0, 0, 0);
                acc[mi][ni] = __builtin_amdgcn_mfma_f32_16x16x32_f16(fal[mi], fbh[ni], acc[mi][ni], 0, 0, 0);
                acc[mi][ni] = __builtin_amdgcn_mfma_f32_16x16x32_f16(fah[mi], fbh[ni], acc[mi][ni], 0, 0, 0);
            }
        __syncthreads();
    }

    const int nn = blockIdx.x;
    #pragma unroll
    for (int ni = 0; ni < 4; ++ni) {
        int col = wn + ni * 16 + fr;
        bool cn = (col < 16);
        float nf = 1.f;
        if (cn) nf = normf[gn0 + col];
        #pragma unroll
        for (int mi = 0; mi < 4; ++mi) {
            #pragma unroll
            for (int r = 0; r < 4; ++r) {
                int gm = gm0 + wm + mi * 16 + fq * 4 + r;
                int mm = gm >> 4, ii = gm & 15;
                float v = acc[mi][ni][r];
                if (cn && col <= ii) v /= nf;
                out[(((size_t)mm * 128 + nn) * 16 + ii) * 128 + col] = v;
            }
        }
    }
}

// ---------------- Kernel 3: wavefront DTW, 4 problems/wave ----------------
// Lane layout: q = lane>>4 (problem within wave), r = lane&15 (row 0..15).
// Anti-diagonal step t: lane computes cell (r, j=t-r). up/diag come from lane r-1
// at steps t-1 / t-2 => shfl_up(D_prev,1) / shfl_up(D_prev2,1). Moves -> LDS bytes.
// Leaders (r==0) backtrack in LDS, record per-row [lo,hi] runs; all lanes then
// write the 0/1 mask as coalesced float4s (path rows are contiguous runs).
__global__ __launch_bounds__(256) void dtw_kernel(float* __restrict__ buf)
{
    __shared__ uint8_t mv_lds[4][4][2064];  // [wave][q][j*16+r], padded stride
    __shared__ int bounds[4][4][16];        // lo | hi<<8 per row

    const int lane = threadIdx.x & 63;
    const int w = threadIdx.x >> 6;
    const int q = lane >> 4, r = lane & 15;
    const int pbase = blockIdx.x * 16 + w * 4;
    const int p = pbase + q;
    float* tile = buf + (size_t)p * 2048;
    const float4* row4 = (const float4*)(tile + r * 128);
    uint8_t* mymv = &mv_lds[w][q][0];

    const double NEG = -1e300;
    double Dp = NEG, Dp2 = NEG;
    float4 cur4 = {0, 0, 0, 0};
    float4 nxt4 = row4[0];

    for (int t = 0; t < 143; ++t) {
        int j = t - r;
        bool act = (j >= 0) & (j < 128);
        if (act & ((j & 3) == 0)) {
            cur4 = nxt4;
            if (j + 4 < 128) nxt4 = row4[(j >> 2) + 1];
        }
        int e = j & 3;
        float sv = (e == 0) ? cur4.x : (e == 1) ? cur4.y : (e == 2) ? cur4.z : cur4.w;
        double up = __shfl_up(Dp, 1);
        double dg = __shfl_up(Dp2, 1);
        double lf = Dp;
        if (r == 0) up = NEG;
        if (j == 0) {
            lf = NEG;
            dg = (r == 0) ? 0.0 : NEG;
        } else if (r == 0) {
            dg = NEG;
        }
        // argmax(up,left,diag), first-max priority (matches np.argmax)
        int m = (up >= lf && up >= dg) ? 0 : ((lf >= dg) ? 1 : 2);
        double Dc = fmax(up, fmax(lf, dg)) + (double)sv;
        if (act) mymv[j * 16 + r] = (uint8_t)m;
        Dp2 = Dp;
        Dp = Dc;
    }
    __syncthreads();

    // backtrack: 4 leader lanes per wave walk their problem's move matrix
    if (r == 0) {
        int i = 16, jj = 128, hic = 127;
        for (int it = 0; it < 160; ++it) {
            if (i <= 0) break;
            int m = mymv[(jj - 1) * 16 + (i - 1)];
            if (m == 1) { --jj; continue; }      // left: stay in row
            bounds[w][q][i - 1] = (jj - 1) | (hic << 8);
            if (m == 2) --jj;                    // diag
            --i;                                 // up or diag
            hic = jj - 1;
        }
    }
    __syncthreads();

    // write masks: 4 problems * 2048 floats = 2048 float4 per wave, coalesced
    #pragma unroll 4
    for (int it = 0; it < 32; ++it) {
        int flat = it * 64 + lane;      // float4 index within wave's 4 problems
        int q2 = flat >> 9;             // 512 float4 per problem
        int rem = flat & 511;
        int ii = rem >> 5;              // 32 float4 per row
        int c4 = rem & 31;
        int b = bounds[w][q2][ii];
        int lo = b & 0xff, hi = (b >> 8) & 0xff;
        int j0 = c4 * 4;
        float4 v;
        v.x = (j0 + 0 >= lo && j0 + 0 <= hi) ? 1.f : 0.f;
        v.y = (j0 + 1 >= lo && j0 + 1 <= hi) ? 1.f : 0.f;
        v.z = (j0 + 2 >= lo && j0 + 2 <= hi) ? 1.f : 0.f;
        v.w = (j0 + 3 >= lo && j0 + 3 <= hi) ? 1.f : 0.f;
        float* tb = buf + (size_t)(pbase + q2) * 2048;
        *(float4*)(tb + ii * 128 + j0) = v;
    }
}

extern "C" void kernel_launch(void* const* d_in, const int* in_sizes, int n_in,
                              void* d_out, int out_size, void* d_ws, size_t ws_size,
                              hipStream_t stream)
{
    const float* c_feats = (const float*)d_in[0];
    const float* f_feats = (const float*)d_in[1];
    float* out = (float*)d_out;

    _Float16* Ah = (_Float16*)d_ws;
    _Float16* Al = Ah + (size_t)M_TOT * K_TOT;
    _Float16* Bh = Al + (size_t)M_TOT * K_TOT;
    _Float16* Bl = Bh + (size_t)N_TOT * K_TOT;
    float* normf = (float*)(Bl + (size_t)N_TOT * K_TOT);

    norm_split_kernel<<<4608, 256, 0, stream>>>(c_feats, f_feats, Ah, Al, Bh, Bl, normf);
    dim3 g(N_TOT / 128, M_TOT / 128);
    mfma_gemm_kernel<<<g, 256, 0, stream>>>(Ah, Al, Bh, Bl, normf, out);
    dtw_kernel<<<1024, 256, 0, stream>>>(out);
}